// Round 3
// baseline (500.891 us; speedup 1.0000x reference)
//
#include <hip/hip_runtime.h>
#include <hip/hip_bf16.h>

typedef __attribute__((ext_vector_type(8))) short short8;
typedef __attribute__((ext_vector_type(4))) float floatx4;

#define LOG2E 1.4426950408889634f

static __device__ __forceinline__ short f2bf(float f) {
    unsigned int u = __float_as_uint(f);
    unsigned int r = u + 0x7FFFu + ((u >> 16) & 1u);
    return (short)(r >> 16);
}
static __device__ __forceinline__ float bf2f(short s) {
    return __uint_as_float(((unsigned int)(unsigned short)s) << 16);
}

static __device__ __forceinline__ void load_lds16(const void* g, void* l) {
    __builtin_amdgcn_global_load_lds(
        (const __attribute__((address_space(1))) unsigned int*)g,
        (__attribute__((address_space(3))) unsigned int*)l, 16, 0, 0);
}

// ---------------- cast f32 -> bf16 (8 elems/thread) ----------------
__global__ void cast_f32_bf16_kernel(const float* __restrict__ in,
                                     short* __restrict__ out, int n8) {
    const int i = blockIdx.x * blockDim.x + threadIdx.x;
    if (i >= n8) return;
    const float4 v0 = *(const float4*)(in + (size_t)i * 8);
    const float4 v1 = *(const float4*)(in + (size_t)i * 8 + 4);
    short8 s;
    s[0] = f2bf(v0.x); s[1] = f2bf(v0.y); s[2] = f2bf(v0.z); s[3] = f2bf(v0.w);
    s[4] = f2bf(v1.x); s[5] = f2bf(v1.y); s[6] = f2bf(v1.z); s[7] = f2bf(v1.w);
    *(short8*)(out + (size_t)i * 8) = s;
}

// ---------------- transpose + cast f32 [R][C] -> bf16 [C][R] ----------------
__global__ void transpose_cast_kernel(const float* __restrict__ in,
                                      short* __restrict__ out, int R, int C) {
    __shared__ float tile[32][33];
    const int tx = threadIdx.x, ty = threadIdx.y;
    const int x = blockIdx.x * 32 + tx;
    const int y0 = blockIdx.y * 32;
#pragma unroll
    for (int j = 0; j < 4; ++j)
        tile[ty + j * 8][tx] = in[(size_t)(y0 + ty + j * 8) * C + x];
    __syncthreads();
#pragma unroll
    for (int j = 0; j < 4; ++j)
        out[(size_t)(blockIdx.x * 32 + ty + j * 8) * R + y0 + tx] =
            f2bf(tile[tx][ty + j * 8]);
}

// ---------------- GEMM (m97 structure): A[M,K] x Bt[N,K] -> C[M,N] (+bias) ----------------
template <int EPI>
__global__ __launch_bounds__(256) void gemm97_kernel(
    const short* __restrict__ A, const short* __restrict__ Bt,
    const float* __restrict__ bias, float* __restrict__ Cf,
    short* __restrict__ Qb, short* __restrict__ Kb, short* __restrict__ Vt,
    int M, int N, int K, int gx) {
    __shared__ __align__(16) short As[128 * 32];
    __shared__ __align__(16) short Bs[128 * 32];

    const int tid = threadIdx.x;
    const int lane = tid & 63, wave = tid >> 6;
    const int wm = wave >> 1, wn = wave & 1;
    const int lr = lane & 15, lk = lane >> 4;

    const int nwg = gridDim.x;
    const int id = blockIdx.x;
    const int swz = (id & 7) * (nwg >> 3) + (id >> 3);
    const int bx = swz % gx, by = swz / gx;
    const int bm0 = by * 128, bn0 = bx * 128;

    const int srow = lane >> 2;
    const int scol = (lane & 3) * 8;

    floatx4 acc[4][4];
#pragma unroll
    for (int m = 0; m < 4; ++m)
#pragma unroll
        for (int n = 0; n < 4; ++n) acc[m][n] = (floatx4){0.f, 0.f, 0.f, 0.f};

    for (int k0 = 0; k0 < K; k0 += 32) {
        __syncthreads();
#pragma unroll
        for (int i = 0; i < 2; ++i) {
            const int chunk = i * 4 + wave;
            load_lds16(A + (size_t)(bm0 + chunk * 16 + srow) * K + k0 + scol,
                       As + chunk * 512);
            load_lds16(Bt + (size_t)(bn0 + chunk * 16 + srow) * K + k0 + scol,
                       Bs + chunk * 512);
        }
        __syncthreads();

        short8 af[4], bfr[4];
#pragma unroll
        for (int m = 0; m < 4; ++m)
            af[m] = *(const short8*)&As[(wm * 64 + m * 16 + lr) * 32 + lk * 8];
#pragma unroll
        for (int n = 0; n < 4; ++n)
            bfr[n] = *(const short8*)&Bs[(wn * 64 + n * 16 + lr) * 32 + lk * 8];
#pragma unroll
        for (int m = 0; m < 4; ++m)
#pragma unroll
            for (int n = 0; n < 4; ++n)
                acc[m][n] = __builtin_amdgcn_mfma_f32_16x16x32_bf16(
                    af[m], bfr[n], acc[m][n], 0, 0, 0);
    }

#pragma unroll
    for (int m = 0; m < 4; ++m)
#pragma unroll
        for (int n = 0; n < 4; ++n)
#pragma unroll
            for (int r = 0; r < 4; ++r) {
                const int row = bm0 + wm * 64 + m * 16 + lk * 4 + r;
                const int col = bn0 + wn * 64 + n * 16 + lr;
                const float val = acc[m][n][r] + bias[col];
                if (EPI == 1) {
                    Cf[(size_t)row * N + col] = val;
                } else {
                    const short bv = f2bf(val);
                    const int t = col >> 11, h = (col >> 7) & 15, dq = col & 127;
                    const int b = row >> 11, s = row & 2047;
                    if (t == 0)
                        Qb[(((size_t)(b * 16 + h)) * 2048 + s) * 128 + dq] = bv;
                    else if (t == 1)
                        Kb[(((size_t)(b * 16 + h)) * 2048 + s) * 128 + dq] = bv;
                    else
                        Vt[(((size_t)(b * 16 + h)) * 128 + dq) * 2048 + s] = bv;
                }
            }
}

// ---------------- RoPE (in-place on bf16 Q and K, [B,H,S,DQ]) ----------------
__global__ void rope_kernel(short* __restrict__ Qb, short* __restrict__ Kb,
                            const int* __restrict__ pos, int total) {
    int i = blockIdx.x * blockDim.x + threadIdx.x;
    short* T = Qb;
    int j = i;
    if (i >= total) { T = Kb; j = i - total; }
    if (j >= total) return;
    const int ih = j & 63;
    const int s = (j >> 6) & 2047;
    const size_t base = ((size_t)(j >> 6)) * 128 + ih;
    const float t1 = bf2f(T[base]);
    const float t2 = bf2f(T[base + 64]);
    const float p = (float)pos[s];
    const float ang = p * exp2f((float)ih * (-13.287712379549449f / 64.0f));
    float sn, cs;
    sincosf(ang, &sn, &cs);
    T[base] = f2bf(t1 * cs - t2 * sn);
    T[base + 64] = f2bf(t1 * sn + t2 * cs);
}

// ---------------- causal flash attention v2 ----------------
// 1-D grid of 1024 blocks, XCD-swizzled: XCD k owns heads 4k..4k+3, qt descending.
// QBLK=64 (4 waves x 16 rows), KVBLK=128. K in LDS, V direct from global (L2).
__global__ __launch_bounds__(256) void attn_kernel(
    const short* __restrict__ Qb, const short* __restrict__ Kb,
    const short* __restrict__ Vt, short* __restrict__ Ob) {
    const int f = blockIdx.x;
    const int swz = (f & 7) * 128 + (f >> 3);   // 1024 blocks
    const int bh = swz >> 5;
    const int qt = 31 - (swz & 31);             // longest blocks first
    const int wave = threadIdx.x >> 6, lane = threadIdx.x & 63;
    const int lr = lane & 15, lk = lane >> 4;
    const int q0 = qt * 64;
    const short* Qh = Qb + (size_t)bh * 2048 * 128;
    const short* Kh = Kb + (size_t)bh * 2048 * 128;
    const short* Vh = Vt + (size_t)bh * 128 * 2048;

    __shared__ __align__(16) short Ks[128][136];
    __shared__ __align__(16) short Ps[4][16][136];

    short8 qf[4];
#pragma unroll
    for (int kc = 0; kc < 4; ++kc)
        qf[kc] = *(const short8*)&Qh[(size_t)(q0 + wave * 16 + lr) * 128 + kc * 32 + lk * 8];

    floatx4 o[8];
#pragma unroll
    for (int d = 0; d < 8; ++d) o[d] = (floatx4){0.f, 0.f, 0.f, 0.f};
    float mrow[4], lrow[4];
#pragma unroll
    for (int r = 0; r < 4; ++r) { mrow[r] = -3.0e38f; lrow[r] = 0.f; }

    const float sl = 0.08838834764831845f * LOG2E;  // scale * log2(e)
    const int nkt = (q0 + 64 + 127) >> 7;

    for (int t = 0; t < nkt; ++t) {
        const int s0 = t * 128;
        __syncthreads();
        {   // stage K tile [128][128] -> Ks[128][136]
            const int r = threadIdx.x >> 1, c = (threadIdx.x & 1) * 64;
            const short* src = Kh + (size_t)(s0 + r) * 128 + c;
#pragma unroll
            for (int i = 0; i < 8; ++i)
                *(short8*)&Ks[r][c + i * 8] = *(const short8*)(src + i * 8);
        }
        __syncthreads();

        // ---- S = Q K^T (log2-scaled) ----
        floatx4 sv[8];
#pragma unroll
        for (int nt = 0; nt < 8; ++nt) {
            floatx4 a = (floatx4){0.f, 0.f, 0.f, 0.f};
#pragma unroll
            for (int kc = 0; kc < 4; ++kc) {
                short8 kf = *(const short8*)&Ks[nt * 16 + lr][kc * 32 + lk * 8];
                a = __builtin_amdgcn_mfma_f32_16x16x32_bf16(qf[kc], kf, a, 0, 0, 0);
            }
            sv[nt] = a;
        }

        const bool last = (t == nkt - 1);
#pragma unroll
        for (int nt = 0; nt < 8; ++nt)
#pragma unroll
            for (int r = 0; r < 4; ++r) {
                float x = sv[nt][r] * sl;
                if (last) {
                    const int col = s0 + nt * 16 + lr;
                    const int row = q0 + wave * 16 + lk * 4 + r;
                    if (col > row) x = -3.0e38f;
                }
                sv[nt][r] = x;
            }

        // ---- online softmax (base-2 domain) ----
        float mnew[4], alpha[4];
#pragma unroll
        for (int r = 0; r < 4; ++r) {
            float tm = fmaxf(fmaxf(fmaxf(sv[0][r], sv[1][r]), fmaxf(sv[2][r], sv[3][r])),
                             fmaxf(fmaxf(sv[4][r], sv[5][r]), fmaxf(sv[6][r], sv[7][r])));
            tm = fmaxf(tm, __shfl_xor(tm, 1));
            tm = fmaxf(tm, __shfl_xor(tm, 2));
            tm = fmaxf(tm, __shfl_xor(tm, 4));
            tm = fmaxf(tm, __shfl_xor(tm, 8));
            const float mn = fmaxf(mrow[r], tm);
            alpha[r] = exp2f(mrow[r] - mn);
            mnew[r] = mn;
            mrow[r] = mn;
        }
#pragma unroll
        for (int r = 0; r < 4; ++r) {
            float rs = 0.f;
#pragma unroll
            for (int nt = 0; nt < 8; ++nt) {
                const float p = exp2f(sv[nt][r] - mnew[r]);
                sv[nt][r] = p;
                rs += p;
            }
            rs += __shfl_xor(rs, 1);
            rs += __shfl_xor(rs, 2);
            rs += __shfl_xor(rs, 4);
            rs += __shfl_xor(rs, 8);
            lrow[r] = lrow[r] * alpha[r] + rs;
        }
#pragma unroll
        for (int d = 0; d < 8; ++d)
#pragma unroll
            for (int r = 0; r < 4; ++r) o[d][r] *= alpha[r];

        // ---- P (C-layout) -> wave-private LDS (no barrier needed) ----
#pragma unroll
        for (int nt = 0; nt < 8; ++nt)
#pragma unroll
            for (int r = 0; r < 4; ++r)
                Ps[wave][lk * 4 + r][nt * 16 + lr] = f2bf(sv[nt][r]);

        // ---- O += P V, V frags direct from global (L2-resident) ----
#pragma unroll
        for (int kc = 0; kc < 4; ++kc) {
            short8 pf = *(const short8*)&Ps[wave][lr][kc * 32 + lk * 8];
            short8 vf[8];
#pragma unroll
            for (int d = 0; d < 8; ++d)
                vf[d] = *(const short8*)&Vh[(size_t)(d * 16 + lr) * 2048 + s0 + kc * 32 + lk * 8];
#pragma unroll
            for (int d = 0; d < 8; ++d)
                o[d] = __builtin_amdgcn_mfma_f32_16x16x32_bf16(pf, vf[d], o[d], 0, 0, 0);
        }
    }

    // ---- epilogue: O/l -> attn_concat [B,S,H*DQ] bf16 ----
    const int b = bh >> 4, h = bh & 15;
#pragma unroll
    for (int d = 0; d < 8; ++d)
#pragma unroll
        for (int r = 0; r < 4; ++r) {
            const int srow = q0 + wave * 16 + lk * 4 + r;
            const float val = o[d][r] / lrow[r];
            Ob[((size_t)(b * 2048 + srow)) * 2048 + h * 128 + d * 16 + lr] = f2bf(val);
        }
}

extern "C" void kernel_launch(void* const* d_in, const int* in_sizes, int n_in,
                              void* d_out, int out_size, void* d_ws, size_t ws_size,
                              hipStream_t stream) {
    const float* x = (const float*)d_in[0];
    const int* rope_pos = (const int*)d_in[1];
    const float* W_qkv = (const float*)d_in[2];
    const float* b_qkv = (const float*)d_in[3];
    const float* W_out = (const float*)d_in[4];
    const float* b_out = (const float*)d_in[5];
    float* out = (float*)d_out;

    char* ws = (char*)d_ws;
    short* Wqkvt = (short*)ws;                                   // 25165824 B
    short* Woutt = (short*)(ws + 25165824);                      // 8388608 B
    short* Qb = (short*)(ws + 25165824 + 8388608);               // 8388608 B each
    short* Kb = Qb + 8388608;
    short* Vt = Kb + 8388608;
    short* Attn = Vt + 8388608;
    short* Xb = Attn;  // alias: Xb dead before attn_kernel writes Attn

    cast_f32_bf16_kernel<<<4096, 256, 0, stream>>>(x, Xb, 1048576);
    transpose_cast_kernel<<<dim3(6144 / 32, 2048 / 32), dim3(32, 8), 0, stream>>>(
        W_qkv, Wqkvt, 2048, 6144);
    transpose_cast_kernel<<<dim3(2048 / 32, 2048 / 32), dim3(32, 8), 0, stream>>>(
        W_out, Woutt, 2048, 2048);
    gemm97_kernel<0><<<1536, 256, 0, stream>>>(
        Xb, Wqkvt, b_qkv, nullptr, Qb, Kb, Vt, 4096, 6144, 2048, 48);
    rope_kernel<<<32768, 256, 0, stream>>>(Qb, Kb, rope_pos, 4194304);
    attn_kernel<<<1024, 256, 0, stream>>>(Qb, Kb, Vt, Attn);
    gemm97_kernel<1><<<512, 256, 0, stream>>>(
        Attn, Woutt, b_out, out, nullptr, nullptr, nullptr, 4096, 2048, 2048, 16);
}

// Round 4
// 395.435 us; speedup vs baseline: 1.2667x; 1.2667x over previous
//
#include <hip/hip_runtime.h>
#include <hip/hip_bf16.h>

typedef __attribute__((ext_vector_type(8))) short short8;
typedef __attribute__((ext_vector_type(4))) float floatx4;

#define LOG2E 1.4426950408889634f

static __device__ __forceinline__ short f2bf(float f) {
    unsigned int u = __float_as_uint(f);
    unsigned int r = u + 0x7FFFu + ((u >> 16) & 1u);
    return (short)(r >> 16);
}
static __device__ __forceinline__ float bf2f(short s) {
    return __uint_as_float(((unsigned int)(unsigned short)s) << 16);
}

static __device__ __forceinline__ void load_lds16(const void* g, void* l) {
    __builtin_amdgcn_global_load_lds(
        (const __attribute__((address_space(1))) unsigned int*)g,
        (__attribute__((address_space(3))) unsigned int*)l, 16, 0, 0);
}

// ---------------- cast f32 -> bf16 (8 elems/thread) ----------------
__global__ void cast_f32_bf16_kernel(const float* __restrict__ in,
                                     short* __restrict__ out, int n8) {
    const int i = blockIdx.x * blockDim.x + threadIdx.x;
    if (i >= n8) return;
    const float4 v0 = *(const float4*)(in + (size_t)i * 8);
    const float4 v1 = *(const float4*)(in + (size_t)i * 8 + 4);
    short8 s;
    s[0] = f2bf(v0.x); s[1] = f2bf(v0.y); s[2] = f2bf(v0.z); s[3] = f2bf(v0.w);
    s[4] = f2bf(v1.x); s[5] = f2bf(v1.y); s[6] = f2bf(v1.z); s[7] = f2bf(v1.w);
    *(short8*)(out + (size_t)i * 8) = s;
}

// ---------------- transpose + cast f32 [R][C] -> bf16 [C][R] ----------------
__global__ void transpose_cast_kernel(const float* __restrict__ in,
                                      short* __restrict__ out, int R, int C) {
    __shared__ float tile[32][33];
    const int tx = threadIdx.x, ty = threadIdx.y;
    const int x = blockIdx.x * 32 + tx;
    const int y0 = blockIdx.y * 32;
#pragma unroll
    for (int j = 0; j < 4; ++j)
        tile[ty + j * 8][tx] = in[(size_t)(y0 + ty + j * 8) * C + x];
    __syncthreads();
#pragma unroll
    for (int j = 0; j < 4; ++j)
        out[(size_t)(blockIdx.x * 32 + ty + j * 8) * R + y0 + tx] =
            f2bf(tile[tx][ty + j * 8]);
}

// ---------------- GEMM (m97 structure): A[M,K] x Bt[N,K] -> C[M,N] (+bias) ----------------
template <int EPI>
__global__ __launch_bounds__(256) void gemm97_kernel(
    const short* __restrict__ A, const short* __restrict__ Bt,
    const float* __restrict__ bias, float* __restrict__ Cf,
    short* __restrict__ Qb, short* __restrict__ Kb, short* __restrict__ Vt,
    int M, int N, int K, int gx) {
    __shared__ __align__(16) short As[128 * 32];
    __shared__ __align__(16) short Bs[128 * 32];

    const int tid = threadIdx.x;
    const int lane = tid & 63, wave = tid >> 6;
    const int wm = wave >> 1, wn = wave & 1;
    const int lr = lane & 15, lk = lane >> 4;

    const int nwg = gridDim.x;
    const int id = blockIdx.x;
    const int swz = (id & 7) * (nwg >> 3) + (id >> 3);
    const int bx = swz % gx, by = swz / gx;
    const int bm0 = by * 128, bn0 = bx * 128;

    const int srow = lane >> 2;
    const int scol = (lane & 3) * 8;

    floatx4 acc[4][4];
#pragma unroll
    for (int m = 0; m < 4; ++m)
#pragma unroll
        for (int n = 0; n < 4; ++n) acc[m][n] = (floatx4){0.f, 0.f, 0.f, 0.f};

    for (int k0 = 0; k0 < K; k0 += 32) {
        __syncthreads();
#pragma unroll
        for (int i = 0; i < 2; ++i) {
            const int chunk = i * 4 + wave;
            load_lds16(A + (size_t)(bm0 + chunk * 16 + srow) * K + k0 + scol,
                       As + chunk * 512);
            load_lds16(Bt + (size_t)(bn0 + chunk * 16 + srow) * K + k0 + scol,
                       Bs + chunk * 512);
        }
        __syncthreads();

        short8 af[4], bfr[4];
#pragma unroll
        for (int m = 0; m < 4; ++m)
            af[m] = *(const short8*)&As[(wm * 64 + m * 16 + lr) * 32 + lk * 8];
#pragma unroll
        for (int n = 0; n < 4; ++n)
            bfr[n] = *(const short8*)&Bs[(wn * 64 + n * 16 + lr) * 32 + lk * 8];
#pragma unroll
        for (int m = 0; m < 4; ++m)
#pragma unroll
            for (int n = 0; n < 4; ++n)
                acc[m][n] = __builtin_amdgcn_mfma_f32_16x16x32_bf16(
                    af[m], bfr[n], acc[m][n], 0, 0, 0);
    }

#pragma unroll
    for (int m = 0; m < 4; ++m)
#pragma unroll
        for (int n = 0; n < 4; ++n)
#pragma unroll
            for (int r = 0; r < 4; ++r) {
                const int row = bm0 + wm * 64 + m * 16 + lk * 4 + r;
                const int col = bn0 + wn * 64 + n * 16 + lr;
                const float val = acc[m][n][r] + bias[col];
                if (EPI == 1) {
                    Cf[(size_t)row * N + col] = val;
                } else {
                    const short bv = f2bf(val);
                    const int t = col >> 11, h = (col >> 7) & 15, dq = col & 127;
                    const int b = row >> 11, s = row & 2047;
                    if (t == 0)
                        Qb[(((size_t)(b * 16 + h)) * 2048 + s) * 128 + dq] = bv;
                    else if (t == 1)
                        Kb[(((size_t)(b * 16 + h)) * 2048 + s) * 128 + dq] = bv;
                    else
                        Vt[(((size_t)(b * 16 + h)) * 128 + dq) * 2048 + s] = bv;
                }
            }
}

// ---------------- RoPE (in-place on bf16 Q and K, [B,H,S,DQ]) ----------------
__global__ void rope_kernel(short* __restrict__ Qb, short* __restrict__ Kb,
                            const int* __restrict__ pos, int total) {
    int i = blockIdx.x * blockDim.x + threadIdx.x;
    short* T = Qb;
    int j = i;
    if (i >= total) { T = Kb; j = i - total; }
    if (j >= total) return;
    const int ih = j & 63;
    const int s = (j >> 6) & 2047;
    const size_t base = ((size_t)(j >> 6)) * 128 + ih;
    const float t1 = bf2f(T[base]);
    const float t2 = bf2f(T[base + 64]);
    const float p = (float)pos[s];
    const float ang = p * exp2f((float)ih * (-13.287712379549449f / 64.0f));
    float sn, cs;
    sincosf(ang, &sn, &cs);
    T[base] = f2bf(t1 * cs - t2 * sn);
    T[base + 64] = f2bf(t1 * sn + t2 * cs);
}

// ---------------- causal flash attention v3 ----------------
// QBLK=64 (4 waves x 16 rows), KVBLK=64. K,V double-buffered in LDS via
// global_load_lds (linear dest + pre-swizzled source; XOR-swizzled ds_read).
// One barrier per KV tile. 1024 blocks, XCD head affinity, longest-qt first.
__global__ __launch_bounds__(256) void attn_kernel(
    const short* __restrict__ Qb, const short* __restrict__ Kb,
    const short* __restrict__ Vt, short* __restrict__ Ob) {
    const int f = blockIdx.x;
    const int swz = (f & 7) * 128 + (f >> 3);   // 1024 blocks
    const int bh = swz >> 5;
    const int qt = 31 - (swz & 31);             // longest blocks first
    const int wave = threadIdx.x >> 6, lane = threadIdx.x & 63;
    const int lr = lane & 15, lk = lane >> 4;
    const int q0 = qt * 64;
    const short* Qh = Qb + (size_t)bh * 2048 * 128;
    const short* Kh = Kb + (size_t)bh * 2048 * 128;
    const short* Vh = Vt + (size_t)bh * 128 * 2048;

    __shared__ __align__(16) short Ks[2][64 * 128];
    __shared__ __align__(16) short Vs[2][128 * 64];
    __shared__ __align__(16) short Ps[4][16][72];

    // per-lane staging sources (pre-swizzled so linear LDS dest yields
    // XOR-swizzled layout: 16B-chunk index ^= (row & 7))
    const char* srcK[4];
    const char* srcV[4];
#pragma unroll
    for (int j = 0; j < 4; ++j) {
        const int rK = wave * 16 + 4 * j + (lane >> 4);     // 0..63
        srcK[j] = (const char*)Kh + (size_t)rK * 256 +
                  (((lane & 15) ^ (rK & 7)) * 16);
        const int rV = wave * 32 + 8 * j + (lane >> 3);     // 0..127 (dq)
        srcV[j] = (const char*)Vh + (size_t)rV * 4096 +
                  (((lane & 7) ^ (rV & 7)) * 16);
    }

    short8 qf[4];
#pragma unroll
    for (int kc = 0; kc < 4; ++kc)
        qf[kc] = *(const short8*)&Qh[(size_t)(q0 + wave * 16 + lr) * 128 + kc * 32 + lk * 8];

    floatx4 o[8];
#pragma unroll
    for (int d = 0; d < 8; ++d) o[d] = (floatx4){0.f, 0.f, 0.f, 0.f};
    float mrow[4], lrow[4];
#pragma unroll
    for (int r = 0; r < 4; ++r) { mrow[r] = -3.0e38f; lrow[r] = 0.f; }

    const float sl = 0.08838834764831845f * LOG2E;  // scale*log2(e)
    const int nkt = qt + 1;
    const int swzk = (lr & 7) << 3;                 // short-index XOR for reads

    // prologue: stage tile 0 into buf 0
#pragma unroll
    for (int j = 0; j < 4; ++j) {
        load_lds16(srcK[j], &Ks[0][(wave * 16 + 4 * j) * 128]);
        load_lds16(srcV[j], &Vs[0][(wave * 32 + 8 * j) * 64]);
    }
    __syncthreads();

    for (int t = 0; t < nkt; ++t) {
        const int cur = t & 1;
        const int s0 = t * 64;
        if (t + 1 < nkt) {  // issue next-tile DMA; lands by end-of-tile barrier
            const size_t offK = (size_t)(t + 1) * 16384;  // 64 rows * 256 B
            const size_t offV = (size_t)(t + 1) * 128;    // 64 cols * 2 B
#pragma unroll
            for (int j = 0; j < 4; ++j) {
                load_lds16(srcK[j] + offK, &Ks[cur ^ 1][(wave * 16 + 4 * j) * 128]);
                load_lds16(srcV[j] + offV, &Vs[cur ^ 1][(wave * 32 + 8 * j) * 64]);
            }
        }

        // ---- S = Q K^T (log2-scaled) ----
        floatx4 sv[4];
#pragma unroll
        for (int nt = 0; nt < 4; ++nt) {
            floatx4 a = (floatx4){0.f, 0.f, 0.f, 0.f};
#pragma unroll
            for (int kc = 0; kc < 4; ++kc) {
                short8 kf = *(const short8*)
                    &Ks[cur][(nt * 16 + lr) * 128 + ((kc * 32 + lk * 8) ^ swzk)];
                a = __builtin_amdgcn_mfma_f32_16x16x32_bf16(qf[kc], kf, a, 0, 0, 0);
            }
            sv[nt] = a;
        }

        const bool last = (t == nkt - 1);
#pragma unroll
        for (int nt = 0; nt < 4; ++nt)
#pragma unroll
            for (int r = 0; r < 4; ++r) {
                float x = sv[nt][r] * sl;
                if (last) {
                    const int col = s0 + nt * 16 + lr;
                    const int row = q0 + wave * 16 + lk * 4 + r;
                    if (col > row) x = -3.0e38f;
                }
                sv[nt][r] = x;
            }

        // ---- online softmax (base-2 domain) ----
        float mnew[4], alpha[4];
#pragma unroll
        for (int r = 0; r < 4; ++r) {
            float tm = fmaxf(fmaxf(sv[0][r], sv[1][r]), fmaxf(sv[2][r], sv[3][r]));
            tm = fmaxf(tm, __shfl_xor(tm, 1));
            tm = fmaxf(tm, __shfl_xor(tm, 2));
            tm = fmaxf(tm, __shfl_xor(tm, 4));
            tm = fmaxf(tm, __shfl_xor(tm, 8));
            const float mn = fmaxf(mrow[r], tm);
            alpha[r] = exp2f(mrow[r] - mn);
            mnew[r] = mn;
            mrow[r] = mn;
        }
#pragma unroll
        for (int r = 0; r < 4; ++r) {
            float rs = 0.f;
#pragma unroll
            for (int nt = 0; nt < 4; ++nt) {
                const float p = exp2f(sv[nt][r] - mnew[r]);
                sv[nt][r] = p;
                rs += p;
            }
            rs += __shfl_xor(rs, 1);
            rs += __shfl_xor(rs, 2);
            rs += __shfl_xor(rs, 4);
            rs += __shfl_xor(rs, 8);
            lrow[r] = lrow[r] * alpha[r] + rs;
        }
#pragma unroll
        for (int d = 0; d < 8; ++d)
#pragma unroll
            for (int r = 0; r < 4; ++r) o[d][r] *= alpha[r];

        // ---- P (C-layout) -> wave-private LDS (lgkmcnt-ordered, no barrier) ----
#pragma unroll
        for (int nt = 0; nt < 4; ++nt)
#pragma unroll
            for (int r = 0; r < 4; ++r)
                Ps[wave][lk * 4 + r][nt * 16 + lr] = f2bf(sv[nt][r]);

        // ---- O += P V ----
#pragma unroll
        for (int kc = 0; kc < 2; ++kc) {
            short8 pf = *(const short8*)&Ps[wave][lr][kc * 32 + lk * 8];
#pragma unroll
            for (int d = 0; d < 8; ++d) {
                short8 vf = *(const short8*)
                    &Vs[cur][(d * 16 + lr) * 64 + ((kc * 32 + lk * 8) ^ swzk)];
                o[d] = __builtin_amdgcn_mfma_f32_16x16x32_bf16(pf, vf, o[d], 0, 0, 0);
            }
        }

        __syncthreads();  // drains next-tile DMA (vmcnt) + syncs LDS readers
    }

    // ---- epilogue: O/l -> attn_concat [B,S,H*DQ] bf16 ----
    const int b = bh >> 4, h = bh & 15;
#pragma unroll
    for (int d = 0; d < 8; ++d)
#pragma unroll
        for (int r = 0; r < 4; ++r) {
            const int srow = q0 + wave * 16 + lk * 4 + r;
            const float val = o[d][r] / lrow[r];
            Ob[((size_t)(b * 2048 + srow)) * 2048 + h * 128 + d * 16 + lr] = f2bf(val);
        }
}

extern "C" void kernel_launch(void* const* d_in, const int* in_sizes, int n_in,
                              void* d_out, int out_size, void* d_ws, size_t ws_size,
                              hipStream_t stream) {
    const float* x = (const float*)d_in[0];
    const int* rope_pos = (const int*)d_in[1];
    const float* W_qkv = (const float*)d_in[2];
    const float* b_qkv = (const float*)d_in[3];
    const float* W_out = (const float*)d_in[4];
    const float* b_out = (const float*)d_in[5];
    float* out = (float*)d_out;

    char* ws = (char*)d_ws;
    short* Wqkvt = (short*)ws;                                   // 25165824 B
    short* Woutt = (short*)(ws + 25165824);                      // 8388608 B
    short* Qb = (short*)(ws + 25165824 + 8388608);               // 8388608 B each
    short* Kb = Qb + 8388608;
    short* Vt = Kb + 8388608;
    short* Attn = Vt + 8388608;
    short* Xb = Attn;  // alias: Xb dead before attn_kernel writes Attn

    cast_f32_bf16_kernel<<<4096, 256, 0, stream>>>(x, Xb, 1048576);
    transpose_cast_kernel<<<dim3(6144 / 32, 2048 / 32), dim3(32, 8), 0, stream>>>(
        W_qkv, Wqkvt, 2048, 6144);
    transpose_cast_kernel<<<dim3(2048 / 32, 2048 / 32), dim3(32, 8), 0, stream>>>(
        W_out, Woutt, 2048, 2048);
    gemm97_kernel<0><<<1536, 256, 0, stream>>>(
        Xb, Wqkvt, b_qkv, nullptr, Qb, Kb, Vt, 4096, 6144, 2048, 48);
    rope_kernel<<<32768, 256, 0, stream>>>(Qb, Kb, rope_pos, 4194304);
    attn_kernel<<<1024, 256, 0, stream>>>(Qb, Kb, Vt, Attn);
    gemm97_kernel<1><<<512, 256, 0, stream>>>(
        Attn, Woutt, b_out, out, nullptr, nullptr, nullptr, 4096, 2048, 2048, 16);
}

// Round 5
// 373.628 us; speedup vs baseline: 1.3406x; 1.0584x over previous
//
#include <hip/hip_runtime.h>
#include <hip/hip_bf16.h>

typedef __attribute__((ext_vector_type(8))) short short8;
typedef __attribute__((ext_vector_type(4))) float floatx4;

#define LOG2E 1.4426950408889634f

static __device__ __forceinline__ short f2bf(float f) {
    unsigned int u = __float_as_uint(f);
    unsigned int r = u + 0x7FFFu + ((u >> 16) & 1u);
    return (short)(r >> 16);
}
static __device__ __forceinline__ float bf2f(short s) {
    return __uint_as_float(((unsigned int)(unsigned short)s) << 16);
}

static __device__ __forceinline__ void load_lds16(const void* g, void* l) {
    __builtin_amdgcn_global_load_lds(
        (const __attribute__((address_space(1))) unsigned int*)g,
        (__attribute__((address_space(3))) unsigned int*)l, 16, 0, 0);
}

// ---------------- cast f32 -> bf16 (8 elems/thread) ----------------
__global__ void cast_f32_bf16_kernel(const float* __restrict__ in,
                                     short* __restrict__ out, int n8) {
    const int i = blockIdx.x * blockDim.x + threadIdx.x;
    if (i >= n8) return;
    const float4 v0 = *(const float4*)(in + (size_t)i * 8);
    const float4 v1 = *(const float4*)(in + (size_t)i * 8 + 4);
    short8 s;
    s[0] = f2bf(v0.x); s[1] = f2bf(v0.y); s[2] = f2bf(v0.z); s[3] = f2bf(v0.w);
    s[4] = f2bf(v1.x); s[5] = f2bf(v1.y); s[6] = f2bf(v1.z); s[7] = f2bf(v1.w);
    *(short8*)(out + (size_t)i * 8) = s;
}

// ---------------- transpose + cast f32 [R][C] -> bf16 [C][R] ----------------
__global__ void transpose_cast_kernel(const float* __restrict__ in,
                                      short* __restrict__ out, int R, int C) {
    __shared__ float tile[32][33];
    const int tx = threadIdx.x, ty = threadIdx.y;
    const int x = blockIdx.x * 32 + tx;
    const int y0 = blockIdx.y * 32;
#pragma unroll
    for (int j = 0; j < 4; ++j)
        tile[ty + j * 8][tx] = in[(size_t)(y0 + ty + j * 8) * C + x];
    __syncthreads();
#pragma unroll
    for (int j = 0; j < 4; ++j)
        out[(size_t)(blockIdx.x * 32 + ty + j * 8) * R + y0 + tx] =
            f2bf(tile[tx][ty + j * 8]);
}

// ------------- GEMM (2-phase dbuf): A[M,K] x Bt[N,K] -> C[M,N] (+bias) -------------
// 128x128 tile, BK=32, double-buffered LDS via global_load_lds width=16.
// STAGE(t+1) issued before compute(t); single barrier per K-step drains DMA.
template <int EPI>
__global__ __launch_bounds__(256) void gemm2p_kernel(
    const short* __restrict__ A, const short* __restrict__ Bt,
    const float* __restrict__ bias, float* __restrict__ Cf,
    short* __restrict__ Qb, short* __restrict__ Kb, short* __restrict__ Vt,
    int M, int N, int K, int gx) {
    __shared__ __align__(16) short As[2][128 * 32];
    __shared__ __align__(16) short Bs[2][128 * 32];

    const int tid = threadIdx.x;
    const int lane = tid & 63, wave = tid >> 6;
    const int wm = wave >> 1, wn = wave & 1;
    const int lr = lane & 15, lk = lane >> 4;

    const int nwg = gridDim.x;
    const int id = blockIdx.x;
    const int swz = (id & 7) * (nwg >> 3) + (id >> 3);
    const int bx = swz % gx, by = swz / gx;
    const int bm0 = by * 128, bn0 = bx * 128;

    // staging: thread covers chunk (wave) and chunk (wave+4); 16-row chunks
    const int srow = lane >> 2;          // 0..15
    const int scol = (lane & 3) * 8;     // 0,8,16,24
    const short* aP0 = A + (size_t)(bm0 + wave * 16 + srow) * K + scol;
    const short* aP1 = aP0 + (size_t)64 * K;
    const short* bP0 = Bt + (size_t)(bn0 + wave * 16 + srow) * K + scol;
    const short* bP1 = bP0 + (size_t)64 * K;

    floatx4 acc[4][4];
#pragma unroll
    for (int m = 0; m < 4; ++m)
#pragma unroll
        for (int n = 0; n < 4; ++n) acc[m][n] = (floatx4){0.f, 0.f, 0.f, 0.f};

    const int nt = K >> 5;

    // prologue: stage tile 0 into buf 0
    load_lds16(aP0, &As[0][wave * 512]);
    load_lds16(aP1, &As[0][(wave + 4) * 512]);
    load_lds16(bP0, &Bs[0][wave * 512]);
    load_lds16(bP1, &Bs[0][(wave + 4) * 512]);
    __syncthreads();

    for (int t = 0; t < nt; ++t) {
        const int cur = t & 1;
        if (t + 1 < nt) {  // prefetch next K-step into other buffer
            const int k = (t + 1) << 5;
            load_lds16(aP0 + k, &As[cur ^ 1][wave * 512]);
            load_lds16(aP1 + k, &As[cur ^ 1][(wave + 4) * 512]);
            load_lds16(bP0 + k, &Bs[cur ^ 1][wave * 512]);
            load_lds16(bP1 + k, &Bs[cur ^ 1][(wave + 4) * 512]);
        }

        short8 af[4], bfr[4];
#pragma unroll
        for (int m = 0; m < 4; ++m)
            af[m] = *(const short8*)&As[cur][(wm * 64 + m * 16 + lr) * 32 + lk * 8];
#pragma unroll
        for (int n = 0; n < 4; ++n)
            bfr[n] = *(const short8*)&Bs[cur][(wn * 64 + n * 16 + lr) * 32 + lk * 8];
#pragma unroll
        for (int m = 0; m < 4; ++m)
#pragma unroll
            for (int n = 0; n < 4; ++n)
                acc[m][n] = __builtin_amdgcn_mfma_f32_16x16x32_bf16(
                    af[m], bfr[n], acc[m][n], 0, 0, 0);

        __syncthreads();  // drains prefetch DMA + syncs LDS readers
    }

#pragma unroll
    for (int m = 0; m < 4; ++m)
#pragma unroll
        for (int n = 0; n < 4; ++n)
#pragma unroll
            for (int r = 0; r < 4; ++r) {
                const int row = bm0 + wm * 64 + m * 16 + lk * 4 + r;
                const int col = bn0 + wn * 64 + n * 16 + lr;
                const float val = acc[m][n][r] + bias[col];
                if (EPI == 1) {
                    Cf[(size_t)row * N + col] = val;
                } else {
                    const short bv = f2bf(val);
                    const int t = col >> 11, h = (col >> 7) & 15, dq = col & 127;
                    const int b = row >> 11, s = row & 2047;
                    if (t == 0)
                        Qb[(((size_t)(b * 16 + h)) * 2048 + s) * 128 + dq] = bv;
                    else if (t == 1)
                        Kb[(((size_t)(b * 16 + h)) * 2048 + s) * 128 + dq] = bv;
                    else
                        Vt[(((size_t)(b * 16 + h)) * 128 + dq) * 2048 + s] = bv;
                }
            }
}

// ---------------- RoPE (in-place on bf16 Q and K, [B,H,S,DQ]) ----------------
__global__ void rope_kernel(short* __restrict__ Qb, short* __restrict__ Kb,
                            const int* __restrict__ pos, int total) {
    int i = blockIdx.x * blockDim.x + threadIdx.x;
    short* T = Qb;
    int j = i;
    if (i >= total) { T = Kb; j = i - total; }
    if (j >= total) return;
    const int ih = j & 63;
    const int s = (j >> 6) & 2047;
    const size_t base = ((size_t)(j >> 6)) * 128 + ih;
    const float t1 = bf2f(T[base]);
    const float t2 = bf2f(T[base + 64]);
    const float p = (float)pos[s];
    const float ang = p * exp2f((float)ih * (-13.287712379549449f / 64.0f));
    float sn, cs;
    sincosf(ang, &sn, &cs);
    T[base] = f2bf(t1 * cs - t2 * sn);
    T[base + 64] = f2bf(t1 * sn + t2 * cs);
}

// ---------------- causal flash attention v3 ----------------
// QBLK=64 (4 waves x 16 rows), KVBLK=64. K,V double-buffered in LDS via
// global_load_lds (linear dest + pre-swizzled source; XOR-swizzled ds_read).
// One barrier per KV tile. 1024 blocks, XCD head affinity, longest-qt first.
__global__ __launch_bounds__(256) void attn_kernel(
    const short* __restrict__ Qb, const short* __restrict__ Kb,
    const short* __restrict__ Vt, short* __restrict__ Ob) {
    const int f = blockIdx.x;
    const int swz = (f & 7) * 128 + (f >> 3);   // 1024 blocks
    const int bh = swz >> 5;
    const int qt = 31 - (swz & 31);             // longest blocks first
    const int wave = threadIdx.x >> 6, lane = threadIdx.x & 63;
    const int lr = lane & 15, lk = lane >> 4;
    const int q0 = qt * 64;
    const short* Qh = Qb + (size_t)bh * 2048 * 128;
    const short* Kh = Kb + (size_t)bh * 2048 * 128;
    const short* Vh = Vt + (size_t)bh * 128 * 2048;

    __shared__ __align__(16) short Ks[2][64 * 128];
    __shared__ __align__(16) short Vs[2][128 * 64];
    __shared__ __align__(16) short Ps[4][16][72];

    const char* srcK[4];
    const char* srcV[4];
#pragma unroll
    for (int j = 0; j < 4; ++j) {
        const int rK = wave * 16 + 4 * j + (lane >> 4);     // 0..63
        srcK[j] = (const char*)Kh + (size_t)rK * 256 +
                  (((lane & 15) ^ (rK & 7)) * 16);
        const int rV = wave * 32 + 8 * j + (lane >> 3);     // 0..127 (dq)
        srcV[j] = (const char*)Vh + (size_t)rV * 4096 +
                  (((lane & 7) ^ (rV & 7)) * 16);
    }

    short8 qf[4];
#pragma unroll
    for (int kc = 0; kc < 4; ++kc)
        qf[kc] = *(const short8*)&Qh[(size_t)(q0 + wave * 16 + lr) * 128 + kc * 32 + lk * 8];

    floatx4 o[8];
#pragma unroll
    for (int d = 0; d < 8; ++d) o[d] = (floatx4){0.f, 0.f, 0.f, 0.f};
    float mrow[4], lrow[4];
#pragma unroll
    for (int r = 0; r < 4; ++r) { mrow[r] = -3.0e38f; lrow[r] = 0.f; }

    const float sl = 0.08838834764831845f * LOG2E;  // scale*log2(e)
    const int nkt = qt + 1;
    const int swzk = (lr & 7) << 3;                 // short-index XOR for reads

    // prologue: stage tile 0 into buf 0
#pragma unroll
    for (int j = 0; j < 4; ++j) {
        load_lds16(srcK[j], &Ks[0][(wave * 16 + 4 * j) * 128]);
        load_lds16(srcV[j], &Vs[0][(wave * 32 + 8 * j) * 64]);
    }
    __syncthreads();

    for (int t = 0; t < nkt; ++t) {
        const int cur = t & 1;
        const int s0 = t * 64;
        if (t + 1 < nkt) {  // issue next-tile DMA; lands by end-of-tile barrier
            const size_t offK = (size_t)(t + 1) * 16384;  // 64 rows * 256 B
            const size_t offV = (size_t)(t + 1) * 128;    // 64 cols * 2 B
#pragma unroll
            for (int j = 0; j < 4; ++j) {
                load_lds16(srcK[j] + offK, &Ks[cur ^ 1][(wave * 16 + 4 * j) * 128]);
                load_lds16(srcV[j] + offV, &Vs[cur ^ 1][(wave * 32 + 8 * j) * 64]);
            }
        }

        // ---- S = Q K^T (log2-scaled) ----
        floatx4 sv[4];
#pragma unroll
        for (int nt = 0; nt < 4; ++nt) {
            floatx4 a = (floatx4){0.f, 0.f, 0.f, 0.f};
#pragma unroll
            for (int kc = 0; kc < 4; ++kc) {
                short8 kf = *(const short8*)
                    &Ks[cur][(nt * 16 + lr) * 128 + ((kc * 32 + lk * 8) ^ swzk)];
                a = __builtin_amdgcn_mfma_f32_16x16x32_bf16(qf[kc], kf, a, 0, 0, 0);
            }
            sv[nt] = a;
        }

        const bool last = (t == nkt - 1);
#pragma unroll
        for (int nt = 0; nt < 4; ++nt)
#pragma unroll
            for (int r = 0; r < 4; ++r) {
                float x = sv[nt][r] * sl;
                if (last) {
                    const int col = s0 + nt * 16 + lr;
                    const int row = q0 + wave * 16 + lk * 4 + r;
                    if (col > row) x = -3.0e38f;
                }
                sv[nt][r] = x;
            }

        // ---- online softmax (base-2 domain) ----
        float mnew[4], alpha[4];
#pragma unroll
        for (int r = 0; r < 4; ++r) {
            float tm = fmaxf(fmaxf(sv[0][r], sv[1][r]), fmaxf(sv[2][r], sv[3][r]));
            tm = fmaxf(tm, __shfl_xor(tm, 1));
            tm = fmaxf(tm, __shfl_xor(tm, 2));
            tm = fmaxf(tm, __shfl_xor(tm, 4));
            tm = fmaxf(tm, __shfl_xor(tm, 8));
            const float mn = fmaxf(mrow[r], tm);
            alpha[r] = exp2f(mrow[r] - mn);
            mnew[r] = mn;
            mrow[r] = mn;
        }
#pragma unroll
        for (int r = 0; r < 4; ++r) {
            float rs = 0.f;
#pragma unroll
            for (int nt = 0; nt < 4; ++nt) {
                const float p = exp2f(sv[nt][r] - mnew[r]);
                sv[nt][r] = p;
                rs += p;
            }
            rs += __shfl_xor(rs, 1);
            rs += __shfl_xor(rs, 2);
            rs += __shfl_xor(rs, 4);
            rs += __shfl_xor(rs, 8);
            lrow[r] = lrow[r] * alpha[r] + rs;
        }
#pragma unroll
        for (int d = 0; d < 8; ++d)
#pragma unroll
            for (int r = 0; r < 4; ++r) o[d][r] *= alpha[r];

        // ---- P (C-layout) -> wave-private LDS (lgkmcnt-ordered, no barrier) ----
#pragma unroll
        for (int nt = 0; nt < 4; ++nt)
#pragma unroll
            for (int r = 0; r < 4; ++r)
                Ps[wave][lk * 4 + r][nt * 16 + lr] = f2bf(sv[nt][r]);

        // ---- O += P V ----
#pragma unroll
        for (int kc = 0; kc < 2; ++kc) {
            short8 pf = *(const short8*)&Ps[wave][lr][kc * 32 + lk * 8];
#pragma unroll
            for (int d = 0; d < 8; ++d) {
                short8 vf = *(const short8*)
                    &Vs[cur][(d * 16 + lr) * 64 + ((kc * 32 + lk * 8) ^ swzk)];
                o[d] = __builtin_amdgcn_mfma_f32_16x16x32_bf16(pf, vf, o[d], 0, 0, 0);
            }
        }

        __syncthreads();  // drains next-tile DMA (vmcnt) + syncs LDS readers
    }

    // ---- epilogue: O/l -> attn_concat [B,S,H*DQ] bf16 ----
    const int b = bh >> 4, h = bh & 15;
#pragma unroll
    for (int d = 0; d < 8; ++d)
#pragma unroll
        for (int r = 0; r < 4; ++r) {
            const int srow = q0 + wave * 16 + lk * 4 + r;
            const float val = o[d][r] / lrow[r];
            Ob[((size_t)(b * 2048 + srow)) * 2048 + h * 128 + d * 16 + lr] = f2bf(val);
        }
}

extern "C" void kernel_launch(void* const* d_in, const int* in_sizes, int n_in,
                              void* d_out, int out_size, void* d_ws, size_t ws_size,
                              hipStream_t stream) {
    const float* x = (const float*)d_in[0];
    const int* rope_pos = (const int*)d_in[1];
    const float* W_qkv = (const float*)d_in[2];
    const float* b_qkv = (const float*)d_in[3];
    const float* W_out = (const float*)d_in[4];
    const float* b_out = (const float*)d_in[5];
    float* out = (float*)d_out;

    char* ws = (char*)d_ws;
    short* Wqkvt = (short*)ws;                                   // 25165824 B
    short* Woutt = (short*)(ws + 25165824);                      // 8388608 B
    short* Qb = (short*)(ws + 25165824 + 8388608);               // 8388608 B each
    short* Kb = Qb + 8388608;
    short* Vt = Kb + 8388608;
    short* Attn = Vt + 8388608;
    short* Xb = Attn;  // alias: Xb dead before attn_kernel writes Attn

    cast_f32_bf16_kernel<<<4096, 256, 0, stream>>>(x, Xb, 1048576);
    transpose_cast_kernel<<<dim3(6144 / 32, 2048 / 32), dim3(32, 8), 0, stream>>>(
        W_qkv, Wqkvt, 2048, 6144);
    transpose_cast_kernel<<<dim3(2048 / 32, 2048 / 32), dim3(32, 8), 0, stream>>>(
        W_out, Woutt, 2048, 2048);
    gemm2p_kernel<0><<<1536, 256, 0, stream>>>(
        Xb, Wqkvt, b_qkv, nullptr, Qb, Kb, Vt, 4096, 6144, 2048, 48);
    rope_kernel<<<32768, 256, 0, stream>>>(Qb, Kb, rope_pos, 4194304);
    attn_kernel<<<1024, 256, 0, stream>>>(Qb, Kb, Vt, Attn);
    gemm2p_kernel<1><<<512, 256, 0, stream>>>(
        Attn, Woutt, b_out, out, nullptr, nullptr, nullptr, 4096, 2048, 2048, 16);
}

// Round 6
// 349.749 us; speedup vs baseline: 1.4321x; 1.0683x over previous
//
#include <hip/hip_runtime.h>
#include <hip/hip_bf16.h>

typedef __attribute__((ext_vector_type(8))) short short8;
typedef __attribute__((ext_vector_type(4))) float floatx4;

#define LOG2E 1.4426950408889634f

static __device__ __forceinline__ short f2bf(float f) {
    unsigned int u = __float_as_uint(f);
    unsigned int r = u + 0x7FFFu + ((u >> 16) & 1u);
    return (short)(r >> 16);
}
static __device__ __forceinline__ float bf2f(short s) {
    return __uint_as_float(((unsigned int)(unsigned short)s) << 16);
}

static __device__ __forceinline__ void load_lds16(const void* g, void* l) {
    __builtin_amdgcn_global_load_lds(
        (const __attribute__((address_space(1))) unsigned int*)g,
        (__attribute__((address_space(3))) unsigned int*)l, 16, 0, 0);
}

// ---------------- cast f32 -> bf16 (8 elems/thread) ----------------
__global__ void cast_f32_bf16_kernel(const float* __restrict__ in,
                                     short* __restrict__ out, int n8) {
    const int i = blockIdx.x * blockDim.x + threadIdx.x;
    if (i >= n8) return;
    const float4 v0 = *(const float4*)(in + (size_t)i * 8);
    const float4 v1 = *(const float4*)(in + (size_t)i * 8 + 4);
    short8 s;
    s[0] = f2bf(v0.x); s[1] = f2bf(v0.y); s[2] = f2bf(v0.z); s[3] = f2bf(v0.w);
    s[4] = f2bf(v1.x); s[5] = f2bf(v1.y); s[6] = f2bf(v1.z); s[7] = f2bf(v1.w);
    *(short8*)(out + (size_t)i * 8) = s;
}

// ---------------- transpose + cast f32 [R][C] -> bf16 [C][R] ----------------
__global__ void transpose_cast_kernel(const float* __restrict__ in,
                                      short* __restrict__ out, int R, int C) {
    __shared__ float tile[32][33];
    const int tx = threadIdx.x, ty = threadIdx.y;
    const int x = blockIdx.x * 32 + tx;
    const int y0 = blockIdx.y * 32;
#pragma unroll
    for (int j = 0; j < 4; ++j)
        tile[ty + j * 8][tx] = in[(size_t)(y0 + ty + j * 8) * C + x];
    __syncthreads();
#pragma unroll
    for (int j = 0; j < 4; ++j)
        out[(size_t)(blockIdx.x * 32 + ty + j * 8) * R + y0 + tx] =
            f2bf(tile[tx][ty + j * 8]);
}

// ------------- GEMM (2-phase dbuf): A[M,K] x Bt[N,K] -> C[M,N] (+bias) -------------
template <int EPI>
__global__ __launch_bounds__(256) void gemm2p_kernel(
    const short* __restrict__ A, const short* __restrict__ Bt,
    const float* __restrict__ bias, float* __restrict__ Cf,
    short* __restrict__ Qb, short* __restrict__ Kb, short* __restrict__ Vt,
    int M, int N, int K, int gx) {
    __shared__ __align__(16) short As[2][128 * 32];
    __shared__ __align__(16) short Bs[2][128 * 32];

    const int tid = threadIdx.x;
    const int lane = tid & 63, wave = tid >> 6;
    const int wm = wave >> 1, wn = wave & 1;
    const int lr = lane & 15, lk = lane >> 4;

    const int nwg = gridDim.x;
    const int id = blockIdx.x;
    const int swz = (id & 7) * (nwg >> 3) + (id >> 3);
    const int bx = swz % gx, by = swz / gx;
    const int bm0 = by * 128, bn0 = bx * 128;

    const int srow = lane >> 2;
    const int scol = (lane & 3) * 8;
    const short* aP0 = A + (size_t)(bm0 + wave * 16 + srow) * K + scol;
    const short* aP1 = aP0 + (size_t)64 * K;
    const short* bP0 = Bt + (size_t)(bn0 + wave * 16 + srow) * K + scol;
    const short* bP1 = bP0 + (size_t)64 * K;

    floatx4 acc[4][4];
#pragma unroll
    for (int m = 0; m < 4; ++m)
#pragma unroll
        for (int n = 0; n < 4; ++n) acc[m][n] = (floatx4){0.f, 0.f, 0.f, 0.f};

    const int nt = K >> 5;

    load_lds16(aP0, &As[0][wave * 512]);
    load_lds16(aP1, &As[0][(wave + 4) * 512]);
    load_lds16(bP0, &Bs[0][wave * 512]);
    load_lds16(bP1, &Bs[0][(wave + 4) * 512]);
    __syncthreads();

    for (int t = 0; t < nt; ++t) {
        const int cur = t & 1;
        if (t + 1 < nt) {
            const int k = (t + 1) << 5;
            load_lds16(aP0 + k, &As[cur ^ 1][wave * 512]);
            load_lds16(aP1 + k, &As[cur ^ 1][(wave + 4) * 512]);
            load_lds16(bP0 + k, &Bs[cur ^ 1][wave * 512]);
            load_lds16(bP1 + k, &Bs[cur ^ 1][(wave + 4) * 512]);
        }

        short8 af[4], bfr[4];
#pragma unroll
        for (int m = 0; m < 4; ++m)
            af[m] = *(const short8*)&As[cur][(wm * 64 + m * 16 + lr) * 32 + lk * 8];
#pragma unroll
        for (int n = 0; n < 4; ++n)
            bfr[n] = *(const short8*)&Bs[cur][(wn * 64 + n * 16 + lr) * 32 + lk * 8];
#pragma unroll
        for (int m = 0; m < 4; ++m)
#pragma unroll
            for (int n = 0; n < 4; ++n)
                acc[m][n] = __builtin_amdgcn_mfma_f32_16x16x32_bf16(
                    af[m], bfr[n], acc[m][n], 0, 0, 0);

        __syncthreads();
    }

#pragma unroll
    for (int m = 0; m < 4; ++m)
#pragma unroll
        for (int n = 0; n < 4; ++n)
#pragma unroll
            for (int r = 0; r < 4; ++r) {
                const int row = bm0 + wm * 64 + m * 16 + lk * 4 + r;
                const int col = bn0 + wn * 64 + n * 16 + lr;
                const float val = acc[m][n][r] + bias[col];
                if (EPI == 1) {
                    Cf[(size_t)row * N + col] = val;
                } else {
                    const short bv = f2bf(val);
                    const int t = col >> 11, h = (col >> 7) & 15, dq = col & 127;
                    const int b = row >> 11, s = row & 2047;
                    if (t == 0)
                        Qb[(((size_t)(b * 16 + h)) * 2048 + s) * 128 + dq] = bv;
                    else if (t == 1)
                        Kb[(((size_t)(b * 16 + h)) * 2048 + s) * 128 + dq] = bv;
                    else
                        Vt[(((size_t)(b * 16 + h)) * 128 + dq) * 2048 + s] = bv;
                }
            }
}

// ---------------- RoPE (in-place; Q additionally scaled by 1/sqrt(D)*log2e) ----------------
__global__ void rope_kernel(short* __restrict__ Qb, short* __restrict__ Kb,
                            const int* __restrict__ pos, int total) {
    int i = blockIdx.x * blockDim.x + threadIdx.x;
    short* T = Qb;
    int j = i;
    float g = 0.08838834764831845f * LOG2E;   // folded into Q only
    if (i >= total) { T = Kb; j = i - total; g = 1.0f; }
    if (j >= total) return;
    const int ih = j & 63;
    const int s = (j >> 6) & 2047;
    const size_t base = ((size_t)(j >> 6)) * 128 + ih;
    const float t1 = bf2f(T[base]);
    const float t2 = bf2f(T[base + 64]);
    const float p = (float)pos[s];
    const float ang = p * exp2f((float)ih * (-13.287712379549449f / 64.0f));
    float sn, cs;
    sincosf(ang, &sn, &cs);
    sn *= g; cs *= g;
    T[base] = f2bf(t1 * cs - t2 * sn);
    T[base + 64] = f2bf(t1 * sn + t2 * cs);
}

// ---------------- causal flash attention v4 ----------------
// QBLK=64 (4 waves x 16 rows), KVBLK=64, dbuf K/V via global_load_lds,
// 1 barrier/tile. Deferred rescale (THR=8), per-lane partial l, truncated P.
__global__ __launch_bounds__(256) void attn_kernel(
    const short* __restrict__ Qb, const short* __restrict__ Kb,
    const short* __restrict__ Vt, short* __restrict__ Ob) {
    const int f = blockIdx.x;
    const int swz = (f & 7) * 128 + (f >> 3);   // 1024 blocks
    const int bh = swz >> 5;
    const int qt = 31 - (swz & 31);             // longest blocks first
    const int wave = threadIdx.x >> 6, lane = threadIdx.x & 63;
    const int lr = lane & 15, lk = lane >> 4;
    const int q0 = qt * 64;
    const short* Qh = Qb + (size_t)bh * 2048 * 128;
    const short* Kh = Kb + (size_t)bh * 2048 * 128;
    const short* Vh = Vt + (size_t)bh * 128 * 2048;

    __shared__ __align__(16) short Ks[2][64 * 128];
    __shared__ __align__(16) short Vs[2][128 * 64];
    __shared__ __align__(16) short Ps[4][16][72];

    const char* srcK[4];
    const char* srcV[4];
#pragma unroll
    for (int j = 0; j < 4; ++j) {
        const int rK = wave * 16 + 4 * j + (lane >> 4);     // 0..63
        srcK[j] = (const char*)Kh + (size_t)rK * 256 +
                  (((lane & 15) ^ (rK & 7)) * 16);
        const int rV = wave * 32 + 8 * j + (lane >> 3);     // 0..127 (dq)
        srcV[j] = (const char*)Vh + (size_t)rV * 4096 +
                  (((lane & 7) ^ (rV & 7)) * 16);
    }

    short8 qf[4];
#pragma unroll
    for (int kc = 0; kc < 4; ++kc)
        qf[kc] = *(const short8*)&Qh[(size_t)(q0 + wave * 16 + lr) * 128 + kc * 32 + lk * 8];

    floatx4 o[8];
#pragma unroll
    for (int d = 0; d < 8; ++d) o[d] = (floatx4){0.f, 0.f, 0.f, 0.f};
    float mrow[4], lrow[4];
#pragma unroll
    for (int r = 0; r < 4; ++r) { mrow[r] = -3.0e38f; lrow[r] = 0.f; }

    const int nkt = qt + 1;
    const int swzk = (lr & 7) << 3;                 // short-index XOR for reads

#pragma unroll
    for (int j = 0; j < 4; ++j) {
        load_lds16(srcK[j], &Ks[0][(wave * 16 + 4 * j) * 128]);
        load_lds16(srcV[j], &Vs[0][(wave * 32 + 8 * j) * 64]);
    }
    __syncthreads();

    for (int t = 0; t < nkt; ++t) {
        const int cur = t & 1;
        const int s0 = t * 64;
        if (t + 1 < nkt) {
            const size_t offK = (size_t)(t + 1) * 16384;
            const size_t offV = (size_t)(t + 1) * 128;
#pragma unroll
            for (int j = 0; j < 4; ++j) {
                load_lds16(srcK[j] + offK, &Ks[cur ^ 1][(wave * 16 + 4 * j) * 128]);
                load_lds16(srcV[j] + offV, &Vs[cur ^ 1][(wave * 32 + 8 * j) * 64]);
            }
        }

        // ---- S = Q K^T (Q pre-scaled to log2 domain) ----
        floatx4 sv[4];
#pragma unroll
        for (int nt = 0; nt < 4; ++nt) {
            floatx4 a = (floatx4){0.f, 0.f, 0.f, 0.f};
#pragma unroll
            for (int kc = 0; kc < 4; ++kc) {
                short8 kf = *(const short8*)
                    &Ks[cur][(nt * 16 + lr) * 128 + ((kc * 32 + lk * 8) ^ swzk)];
                a = __builtin_amdgcn_mfma_f32_16x16x32_bf16(qf[kc], kf, a, 0, 0, 0);
            }
            sv[nt] = a;
        }

        if (t == nkt - 1) {  // causal mask, last tile only
#pragma unroll
            for (int nt = 0; nt < 4; ++nt)
#pragma unroll
                for (int r = 0; r < 4; ++r) {
                    const int col = s0 + nt * 16 + lr;
                    const int row = q0 + wave * 16 + lk * 4 + r;
                    if (col > row) sv[nt][r] = -3.0e38f;
                }
        }

        // ---- tile max (cross-lr reduce) ----
        float tm[4];
#pragma unroll
        for (int r = 0; r < 4; ++r) {
            float v = fmaxf(fmaxf(sv[0][r], sv[1][r]), fmaxf(sv[2][r], sv[3][r]));
            v = fmaxf(v, __shfl_xor(v, 1));
            v = fmaxf(v, __shfl_xor(v, 2));
            v = fmaxf(v, __shfl_xor(v, 4));
            v = fmaxf(v, __shfl_xor(v, 8));
            tm[r] = v;
        }

        // ---- deferred rescale (THR=8): only when max grows past threshold ----
        const bool ok = (tm[0] <= mrow[0] + 8.f) && (tm[1] <= mrow[1] + 8.f) &&
                        (tm[2] <= mrow[2] + 8.f) && (tm[3] <= mrow[3] + 8.f);
        if (!__all(ok)) {
            float alpha[4];
#pragma unroll
            for (int r = 0; r < 4; ++r) {
                const float mn = fmaxf(mrow[r], tm[r]);
                alpha[r] = exp2f(mrow[r] - mn);
                mrow[r] = mn;
                lrow[r] *= alpha[r];
            }
#pragma unroll
            for (int d = 0; d < 8; ++d)
#pragma unroll
                for (int r = 0; r < 4; ++r) o[d][r] *= alpha[r];
        }

        // ---- P = exp2(S - m); per-lane partial l; truncated bf16 P ----
#pragma unroll
        for (int r = 0; r < 4; ++r) {
            float rs = 0.f;
#pragma unroll
            for (int nt = 0; nt < 4; ++nt) {
                const float p = exp2f(sv[nt][r] - mrow[r]);
                sv[nt][r] = p;
                rs += p;
            }
            lrow[r] += rs;  // cross-lane reduce deferred to epilogue
        }
#pragma unroll
        for (int nt = 0; nt < 4; ++nt)
#pragma unroll
            for (int r = 0; r < 4; ++r)
                Ps[wave][lk * 4 + r][nt * 16 + lr] =
                    (short)(__float_as_uint(sv[nt][r]) >> 16);

        // ---- O += P V ----
#pragma unroll
        for (int kc = 0; kc < 2; ++kc) {
            short8 pf = *(const short8*)&Ps[wave][lr][kc * 32 + lk * 8];
#pragma unroll
            for (int d = 0; d < 8; ++d) {
                short8 vf = *(const short8*)
                    &Vs[cur][(d * 16 + lr) * 64 + ((kc * 32 + lk * 8) ^ swzk)];
                o[d] = __builtin_amdgcn_mfma_f32_16x16x32_bf16(pf, vf, o[d], 0, 0, 0);
            }
        }

        __syncthreads();
    }

    // ---- epilogue: reduce l across lanes, O/l -> [B,S,H*DQ] bf16 ----
    float linv[4];
#pragma unroll
    for (int r = 0; r < 4; ++r) {
        float l = lrow[r];
        l += __shfl_xor(l, 1);
        l += __shfl_xor(l, 2);
        l += __shfl_xor(l, 4);
        l += __shfl_xor(l, 8);
        linv[r] = 1.0f / l;
    }
    const int b = bh >> 4, h = bh & 15;
#pragma unroll
    for (int d = 0; d < 8; ++d)
#pragma unroll
        for (int r = 0; r < 4; ++r) {
            const int srow = q0 + wave * 16 + lk * 4 + r;
            const float val = o[d][r] * linv[r];
            Ob[((size_t)(b * 2048 + srow)) * 2048 + h * 128 + d * 16 + lr] = f2bf(val);
        }
}

extern "C" void kernel_launch(void* const* d_in, const int* in_sizes, int n_in,
                              void* d_out, int out_size, void* d_ws, size_t ws_size,
                              hipStream_t stream) {
    const float* x = (const float*)d_in[0];
    const int* rope_pos = (const int*)d_in[1];
    const float* W_qkv = (const float*)d_in[2];
    const float* b_qkv = (const float*)d_in[3];
    const float* W_out = (const float*)d_in[4];
    const float* b_out = (const float*)d_in[5];
    float* out = (float*)d_out;

    char* ws = (char*)d_ws;
    short* Wqkvt = (short*)ws;                                   // 25165824 B
    short* Woutt = (short*)(ws + 25165824);                      // 8388608 B
    short* Qb = (short*)(ws + 25165824 + 8388608);               // 8388608 B each
    short* Kb = Qb + 8388608;
    short* Vt = Kb + 8388608;
    short* Attn = Vt + 8388608;
    short* Xb = Attn;  // alias: Xb dead before attn_kernel writes Attn

    cast_f32_bf16_kernel<<<4096, 256, 0, stream>>>(x, Xb, 1048576);
    transpose_cast_kernel<<<dim3(6144 / 32, 2048 / 32), dim3(32, 8), 0, stream>>>(
        W_qkv, Wqkvt, 2048, 6144);
    transpose_cast_kernel<<<dim3(2048 / 32, 2048 / 32), dim3(32, 8), 0, stream>>>(
        W_out, Woutt, 2048, 2048);
    gemm2p_kernel<0><<<1536, 256, 0, stream>>>(
        Xb, Wqkvt, b_qkv, nullptr, Qb, Kb, Vt, 4096, 6144, 2048, 48);
    rope_kernel<<<32768, 256, 0, stream>>>(Qb, Kb, rope_pos, 4194304);
    attn_kernel<<<1024, 256, 0, stream>>>(Qb, Kb, Vt, Attn);
    gemm2p_kernel<1><<<512, 256, 0, stream>>>(
        Attn, Woutt, b_out, out, nullptr, nullptr, nullptr, 4096, 2048, 2048, 16);
}